// Round 3
// baseline (816.830 us; speedup 1.0000x reference)
//
#include <hip/hip_runtime.h>
#include <math.h>

#define HD 64
#define FIN 512
#define NC 40

struct __align__(8) EdgeT { int s; float v; };

__device__ __forceinline__ float bf2f(ushort u) {
    return __uint_as_float(((unsigned int)u) << 16);
}
__device__ __forceinline__ ushort f2bf(float f) {
    unsigned int u = __float_as_uint(f);
    unsigned int r = (u + 0x7fffu + ((u >> 16) & 1u)) >> 16;   // RNE
    return (ushort)r;
}

// ---------------- graph preprocessing ----------------

__global__ __launch_bounds__(256) void init_kernel(float* deg, int* counts, int n) {
    int i = blockIdx.x * 256 + threadIdx.x;
    if (i < n) { deg[i] = 1.0f; counts[i] = 0; }   // self-loop weight 1
}

__global__ __launch_bounds__(256) void hist_kernel(const int* __restrict__ dst,
        const float* __restrict__ w, float* deg, int* counts, int E) {
    int i = blockIdx.x * 256 + threadIdx.x;
    if (i < E) {
        int d = dst[i];
        atomicAdd(&deg[d], w[i]);
        atomicAdd(&counts[d], 1);
    }
}

__global__ __launch_bounds__(256) void dinv_kernel(const float* __restrict__ deg,
        float* __restrict__ dinv, int n) {
    int i = blockIdx.x * 256 + threadIdx.x;
    if (i < n) { float d = deg[i]; dinv[i] = d > 0.f ? rsqrtf(d) : 0.f; }
}

__global__ __launch_bounds__(256) void scan_block_kernel(const int* __restrict__ counts,
        int* __restrict__ row_ptr, int* __restrict__ bsums, int n) {
    __shared__ int s[256];
    int t = threadIdx.x;
    int i = blockIdx.x * 256 + t;
    int v = (i < n) ? counts[i] : 0;
    s[t] = v; __syncthreads();
    for (int off = 1; off < 256; off <<= 1) {
        int u = (t >= off) ? s[t - off] : 0;
        __syncthreads();
        s[t] += u;
        __syncthreads();
    }
    if (i < n) row_ptr[i] = s[t] - v;
    if (t == 255) bsums[blockIdx.x] = s[255];
}

__global__ __launch_bounds__(512) void scan_top_kernel(int* bsums, int nb) {
    __shared__ int s[512];
    int t = threadIdx.x;
    int v = (t < nb) ? bsums[t] : 0;
    s[t] = v; __syncthreads();
    for (int off = 1; off < 512; off <<= 1) {
        int u = (t >= off) ? s[t - off] : 0;
        __syncthreads();
        s[t] += u;
        __syncthreads();
    }
    if (t < nb) bsums[t] = s[t] - v;
}

__global__ __launch_bounds__(256) void scan_add_kernel(int* __restrict__ row_ptr,
        const int* __restrict__ bsums, int* __restrict__ cursor, int n, int E) {
    int i = blockIdx.x * 256 + threadIdx.x;
    if (i < n) {
        int v = row_ptr[i] + bsums[blockIdx.x];
        row_ptr[i] = v;
        cursor[i] = v;
    }
    if (i == 0) row_ptr[n] = E;
}

__global__ __launch_bounds__(256) void scatter_kernel(const int* __restrict__ src,
        const int* __restrict__ dst, const float* __restrict__ w,
        const float* __restrict__ dinv, int* __restrict__ cursor,
        EdgeT* __restrict__ ed, int E) {
    int i = blockIdx.x * 256 + threadIdx.x;
    if (i < E) {
        int s = src[i], d = dst[i];
        int pos = atomicAdd(&cursor[d], 1);
        EdgeT e; e.s = s; e.v = dinv[s] * w[i] * dinv[d];
        ed[pos] = e;
    }
}

__global__ __launch_bounds__(256) void pad_kernel(const float* __restrict__ Wo,
        const float* __restrict__ bo, float* __restrict__ Wo_pad,
        float* __restrict__ bo_pad) {
    int i = blockIdx.x * 256 + threadIdx.x;
    if (i < HD * HD) {
        int k = i >> 6, c = i & 63;
        Wo_pad[i] = (c < NC) ? Wo[k * NC + c] : 0.f;
    }
    if (i < HD) bo_pad[i] = (i < NC) ? bo[i] : 0.f;
}

// ---------------- SpMM (bf16 h): sup = 0.9*(Ahat @ h_in) + 0.1*h0 ----------------

__global__ __launch_bounds__(256) void spmm_kernel(const ushort* __restrict__ h_in,
        const ushort* __restrict__ h0, ushort* __restrict__ sup,
        const float* __restrict__ dinv, const int* __restrict__ row_ptr,
        const EdgeT* __restrict__ ed, int n) {
    const int lane = threadIdx.x & 63;
    int wid = (blockIdx.x * 256 + threadIdx.x) >> 6;
    int nw = (gridDim.x * 256) >> 6;
    for (int node = wid; node < n; node += nw) {
        float di = dinv[node];
        float a0 = di * di * bf2f(h_in[(size_t)node * HD + lane]);
        float a1 = 0.f, a2 = 0.f, a3 = 0.f;
        int e = row_ptr[node], end = row_ptr[node + 1];
        for (; e + 4 <= end; e += 4) {
            EdgeT E0 = ed[e], E1 = ed[e + 1], E2 = ed[e + 2], E3 = ed[e + 3];
            a0 = fmaf(E0.v, bf2f(h_in[(size_t)E0.s * HD + lane]), a0);
            a1 = fmaf(E1.v, bf2f(h_in[(size_t)E1.s * HD + lane]), a1);
            a2 = fmaf(E2.v, bf2f(h_in[(size_t)E2.s * HD + lane]), a2);
            a3 = fmaf(E3.v, bf2f(h_in[(size_t)E3.s * HD + lane]), a3);
        }
        for (; e < end; ++e) {
            EdgeT E0 = ed[e];
            a0 = fmaf(E0.v, bf2f(h_in[(size_t)E0.s * HD + lane]), a0);
        }
        float acc = (a0 + a1) + (a2 + a3);
        float r = fmaf(0.9f, acc, 0.1f * bf2f(h0[(size_t)node * HD + lane]));
        sup[(size_t)node * HD + lane] = f2bf(r);
    }
}

// ---------------- proj: h0 = relu(x @ W_in + b_in), x fp32, out bf16 ----------------
// 64-node tile, 256 threads, 4x4 thread tile, K-chunks of 64.

__global__ __launch_bounds__(256) void proj_kernel(const float* __restrict__ x,
        const float* __restrict__ W, const float* __restrict__ bias,
        ushort* __restrict__ h0, int n) {
    __shared__ float Af[64 * 68];      // padded stride 68
    __shared__ float Wl[64 * 64];
    const int tid = threadIdx.x;
    const int tx = tid & 15;           // 16 out-groups of 4
    const int ty = tid >> 4;           // 16 node-groups of 4
    const int base = blockIdx.x * 64;
    const int kq = (tid & 15) * 4;
    const int rw = tid >> 4;

    float acc[4][4];
#pragma unroll
    for (int i = 0; i < 4; ++i)
#pragma unroll
        for (int j = 0; j < 4; ++j) acc[i][j] = 0.f;

    for (int kc = 0; kc < FIN; kc += 64) {
        __syncthreads();
#pragma unroll
        for (int p = 0; p < 4; ++p) {
            int row = rw + p * 16;
            int ng = base + row; if (ng >= n) ng = n - 1;
            *(float4*)(Af + row * 68 + kq) =
                *(const float4*)(x + (size_t)ng * FIN + kc + kq);
            *(float4*)(Wl + row * 64 + kq) =
                *(const float4*)(W + (size_t)(kc + row) * HD + kq);
        }
        __syncthreads();
#pragma unroll
        for (int kk = 0; kk < 64; kk += 4) {
            float4 a4[4];
#pragma unroll
            for (int i = 0; i < 4; ++i)
                a4[i] = *(const float4*)(Af + (ty * 4 + i) * 68 + kk);
#pragma unroll
            for (int k2 = 0; k2 < 4; ++k2) {
                float w[4];
                *(float4*)w = *(const float4*)(Wl + (kk + k2) * 64 + tx * 4);
#pragma unroll
                for (int i = 0; i < 4; ++i) {
                    float a = ((const float*)&a4[i])[k2];
#pragma unroll
                    for (int j = 0; j < 4; ++j) acc[i][j] = fmaf(a, w[j], acc[i][j]);
                }
            }
        }
    }

    float b[4];
#pragma unroll
    for (int j = 0; j < 4; ++j) b[j] = bias[tx * 4 + j];
#pragma unroll
    for (int i = 0; i < 4; ++i) {
        int ng = base + ty * 4 + i;
        if (ng < n) {
            ushort4 r;
            r.x = f2bf(fmaxf(acc[i][0] + b[0], 0.f));
            r.y = f2bf(fmaxf(acc[i][1] + b[1], 0.f));
            r.z = f2bf(fmaxf(acc[i][2] + b[2], 0.f));
            r.w = f2bf(fmaxf(acc[i][3] + b[3], 0.f));
            *(ushort4*)(h0 + (size_t)ng * HD + tx * 4) = r;
        }
    }
}

// ---------------- layer / output GEMM over bf16 A, fp32 W, K=64 ----------------
// MODE 1: relu(beta*acc + (1-beta)*A) -> C (bf16, in-place safe)
// MODE 2: log_softmax(acc + bias) over first NC cols -> outp fp32

template<int MODE>
__global__ __launch_bounds__(256) void lgemm_kernel(const ushort* __restrict__ A,
        const float* __restrict__ W, const float* __restrict__ bias,
        ushort* __restrict__ C, float* __restrict__ outp, int n, float beta) {
    __shared__ float Af[64 * 68];
    __shared__ float Wl[64 * 64];
    const int tid = threadIdx.x;
    const int tx = tid & 15;
    const int ty = tid >> 4;
    const int base = blockIdx.x * 64;
    const int kq = (tid & 15) * 4;
    const int rw = tid >> 4;

#pragma unroll
    for (int p = 0; p < 4; ++p) {
        int row = rw + p * 16;
        int ng = base + row; if (ng >= n) ng = n - 1;
        ushort4 u = *(const ushort4*)(A + (size_t)ng * HD + kq);
        Af[row * 68 + kq + 0] = bf2f(u.x);
        Af[row * 68 + kq + 1] = bf2f(u.y);
        Af[row * 68 + kq + 2] = bf2f(u.z);
        Af[row * 68 + kq + 3] = bf2f(u.w);
        *(float4*)(Wl + row * 64 + kq) =
            *(const float4*)(W + (size_t)row * HD + kq);
    }
    __syncthreads();

    float acc[4][4];
#pragma unroll
    for (int i = 0; i < 4; ++i)
#pragma unroll
        for (int j = 0; j < 4; ++j) acc[i][j] = 0.f;

#pragma unroll
    for (int kk = 0; kk < 64; kk += 4) {
        float4 a4[4];
#pragma unroll
        for (int i = 0; i < 4; ++i)
            a4[i] = *(const float4*)(Af + (ty * 4 + i) * 68 + kk);
#pragma unroll
        for (int k2 = 0; k2 < 4; ++k2) {
            float w[4];
            *(float4*)w = *(const float4*)(Wl + (kk + k2) * 64 + tx * 4);
#pragma unroll
            for (int i = 0; i < 4; ++i) {
                float a = ((const float*)&a4[i])[k2];
#pragma unroll
                for (int j = 0; j < 4; ++j) acc[i][j] = fmaf(a, w[j], acc[i][j]);
            }
        }
    }

    if constexpr (MODE == 1) {
        const float ombeta = 1.f - beta;
#pragma unroll
        for (int i = 0; i < 4; ++i) {
            int ng = base + ty * 4 + i;
            if (ng < n) {
                ushort4 r;
                float s0 = Af[(ty * 4 + i) * 68 + tx * 4 + 0];
                float s1 = Af[(ty * 4 + i) * 68 + tx * 4 + 1];
                float s2 = Af[(ty * 4 + i) * 68 + tx * 4 + 2];
                float s3 = Af[(ty * 4 + i) * 68 + tx * 4 + 3];
                r.x = f2bf(fmaxf(fmaf(beta, acc[i][0], ombeta * s0), 0.f));
                r.y = f2bf(fmaxf(fmaf(beta, acc[i][1], ombeta * s1), 0.f));
                r.z = f2bf(fmaxf(fmaf(beta, acc[i][2], ombeta * s2), 0.f));
                r.w = f2bf(fmaxf(fmaf(beta, acc[i][3], ombeta * s3), 0.f));
                *(ushort4*)(C + (size_t)ng * HD + tx * 4) = r;
            }
        }
    } else {
        float b[4];
#pragma unroll
        for (int j = 0; j < 4; ++j) b[j] = bias[tx * 4 + j];
        const bool valid = (tx < 10);   // cols tx*4..tx*4+3 < 40
#pragma unroll
        for (int i = 0; i < 4; ++i) {
            float lo[4];
            float m = -3.0e38f;
#pragma unroll
            for (int j = 0; j < 4; ++j) {
                lo[j] = acc[i][j] + b[j];
                if (valid) m = fmaxf(m, lo[j]);
            }
#pragma unroll
            for (int off = 1; off < 16; off <<= 1)
                m = fmaxf(m, __shfl_xor(m, off, 64));
            float s = 0.f;
            if (valid) {
#pragma unroll
                for (int j = 0; j < 4; ++j) s += __expf(lo[j] - m);
            }
#pragma unroll
            for (int off = 1; off < 16; off <<= 1)
                s += __shfl_xor(s, off, 64);
            float lse = __logf(s);
            int ng = base + ty * 4 + i;
            if (ng < n && valid) {
                float4 r;
                r.x = lo[0] - m - lse; r.y = lo[1] - m - lse;
                r.z = lo[2] - m - lse; r.w = lo[3] - m - lse;
                *(float4*)(outp + (size_t)ng * NC + tx * 4) = r;
            }
        }
    }
}

// ---------------- launch ----------------

extern "C" void kernel_launch(void* const* d_in, const int* in_sizes, int n_in,
                              void* d_out, int out_size, void* d_ws, size_t ws_size,
                              hipStream_t stream) {
    const float* x        = (const float*)d_in[0];
    const int*   eidx     = (const int*)d_in[1];
    const float* ew       = (const float*)d_in[2];
    const float* W_in     = (const float*)d_in[3];
    const float* b_in     = (const float*)d_in[4];
    const float* W_layers = (const float*)d_in[5];
    const float* W_out    = (const float*)d_in[6];
    const float* b_out    = (const float*)d_in[7];
    float* out = (float*)d_out;

    const int N = in_sizes[0] / FIN;
    const int E = in_sizes[2];
    const int L = in_sizes[5] / (HD * HD);
    const int* src = eidx;
    const int* dst = eidx + E;

    size_t off = 0;
    auto carve = [&](size_t bytes) {
        void* p = (char*)d_ws + off;
        off += (bytes + 255) & ~(size_t)255;
        return p;
    };
    float*  deg     = (float*)carve((size_t)N * 4);
    float*  dinv    = (float*)carve((size_t)N * 4);
    int*    counts  = (int*)  carve((size_t)N * 4);
    int*    cursor  = (int*)  carve((size_t)N * 4);
    int*    row_ptr = (int*)  carve((size_t)(N + 1) * 4);
    int*    bsums   = (int*)  carve(512 * 4);
    float*  Wo_pad  = (float*)carve((size_t)HD * HD * 4);
    float*  bo_pad  = (float*)carve((size_t)HD * 4);
    EdgeT*  ed      = (EdgeT*)carve((size_t)E * 8);
    ushort* h0      = (ushort*)carve((size_t)N * HD * 2);
    ushort* hA      = (ushort*)carve((size_t)N * HD * 2);
    ushort* hB      = (ushort*)carve((size_t)N * HD * 2);
    (void)ws_size;

    const int NB = (N + 255) / 256;
    const int EB = (E + 255) / 256;

    init_kernel<<<NB, 256, 0, stream>>>(deg, counts, N);
    hist_kernel<<<EB, 256, 0, stream>>>(dst, ew, deg, counts, E);
    dinv_kernel<<<NB, 256, 0, stream>>>(deg, dinv, N);
    scan_block_kernel<<<NB, 256, 0, stream>>>(counts, row_ptr, bsums, N);
    scan_top_kernel<<<1, 512, 0, stream>>>(bsums, NB);
    scan_add_kernel<<<NB, 256, 0, stream>>>(row_ptr, bsums, cursor, N, E);
    scatter_kernel<<<EB, 256, 0, stream>>>(src, dst, ew, dinv, cursor, ed, E);
    pad_kernel<<<16, 256, 0, stream>>>(W_out, b_out, Wo_pad, bo_pad);

    const int NT = (N + 63) / 64;      // 64-node tiles

    proj_kernel<<<NT, 256, 0, stream>>>(x, W_in, b_in, h0, N);

    const ushort* cur = h0;
    ushort* bufs[2] = { hA, hB };
    for (int i = 0; i < L; ++i) {
        float beta = logf(0.5f / (float)(i + 1) + 1.0f);
        ushort* sup = bufs[i & 1];
        spmm_kernel<<<2048, 256, 0, stream>>>(cur, h0, sup, dinv, row_ptr, ed, N);
        lgemm_kernel<1><<<NT, 256, 0, stream>>>(sup, W_layers + (size_t)i * HD * HD,
                                                nullptr, sup, nullptr, N, beta);
        cur = sup;
    }

    lgemm_kernel<2><<<NT, 256, 0, stream>>>(cur, Wo_pad, bo_pad, nullptr, out, N, 0.f);
}

// Round 4
// 713.230 us; speedup vs baseline: 1.1453x; 1.1453x over previous
//
#include <hip/hip_runtime.h>
#include <math.h>

#define HD 64
#define FIN 512
#define NC 40

struct __align__(8) EdgeT { int s; float v; };

__device__ __forceinline__ float bf2f(ushort u) {
    return __uint_as_float(((unsigned int)u) << 16);
}
__device__ __forceinline__ ushort f2bf(float f) {
    unsigned int u = __float_as_uint(f);
    unsigned int r = (u + 0x7fffu + ((u >> 16) & 1u)) >> 16;   // RNE
    return (ushort)r;
}

// ---------------- graph preprocessing ----------------
// packed[i]: bits[48:64) = edge count, bits[0:48) = fixed-point(2^-32) weighted degree.

__global__ __launch_bounds__(256) void initp_kernel(unsigned long long* packed, int n) {
    int i = blockIdx.x * 256 + threadIdx.x;
    if (i < n) packed[i] = (1ULL << 32);   // self-loop weight 1.0 in fixed point
}

__global__ __launch_bounds__(256) void histp_kernel(const int* __restrict__ dst,
        const float* __restrict__ w, unsigned long long* packed,
        ushort* __restrict__ rank, int E) {
    int i = blockIdx.x * 256 + threadIdx.x;
    if (i < E) {
        int d = dst[i];
        unsigned long long add = (1ULL << 48) |
            (unsigned long long)(w[i] * 4294967296.0f);
        unsigned long long old = atomicAdd(&packed[d], add);
        rank[i] = (ushort)(old >> 48);
    }
}

__global__ __launch_bounds__(256) void dinvp_kernel(const unsigned long long* __restrict__ packed,
        float* __restrict__ dinv, int n) {
    int i = blockIdx.x * 256 + threadIdx.x;
    if (i < n) {
        unsigned long long p = packed[i];
        float deg = (float)((double)(p & 0xFFFFFFFFFFFFULL) * (1.0 / 4294967296.0));
        dinv[i] = deg > 0.f ? rsqrtf(deg) : 0.f;
    }
}

__global__ __launch_bounds__(256) void scan_block_kernel(const unsigned long long* __restrict__ packed,
        int* __restrict__ row_ptr, int* __restrict__ bsums, int n) {
    __shared__ int s[256];
    int t = threadIdx.x;
    int i = blockIdx.x * 256 + t;
    int v = (i < n) ? (int)(packed[i] >> 48) : 0;
    s[t] = v; __syncthreads();
    for (int off = 1; off < 256; off <<= 1) {
        int u = (t >= off) ? s[t - off] : 0;
        __syncthreads();
        s[t] += u;
        __syncthreads();
    }
    if (i < n) row_ptr[i] = s[t] - v;
    if (t == 255) bsums[blockIdx.x] = s[255];
}

__global__ __launch_bounds__(512) void scan_top_kernel(int* bsums, int nb) {
    __shared__ int s[512];
    int t = threadIdx.x;
    int v = (t < nb) ? bsums[t] : 0;
    s[t] = v; __syncthreads();
    for (int off = 1; off < 512; off <<= 1) {
        int u = (t >= off) ? s[t - off] : 0;
        __syncthreads();
        s[t] += u;
        __syncthreads();
    }
    if (t < nb) bsums[t] = s[t] - v;
}

__global__ __launch_bounds__(256) void scan_add_kernel(int* __restrict__ row_ptr,
        const int* __restrict__ bsums, int n, int E) {
    int i = blockIdx.x * 256 + threadIdx.x;
    if (i < n) row_ptr[i] += bsums[blockIdx.x];
    if (i == 0) row_ptr[n] = E;
}

__global__ __launch_bounds__(256) void scatter_kernel(const int* __restrict__ src,
        const int* __restrict__ dst, const float* __restrict__ w,
        const float* __restrict__ dinv, const int* __restrict__ row_ptr,
        const ushort* __restrict__ rank, EdgeT* __restrict__ ed, int E) {
    int i = blockIdx.x * 256 + threadIdx.x;
    if (i < E) {
        int s = src[i], d = dst[i];
        int pos = row_ptr[d] + (int)rank[i];
        EdgeT e; e.s = s; e.v = dinv[s] * w[i] * dinv[d];
        ed[pos] = e;
    }
}

__global__ __launch_bounds__(256) void pad_kernel(const float* __restrict__ Wo,
        const float* __restrict__ bo, float* __restrict__ Wo_pad,
        float* __restrict__ bo_pad) {
    int i = blockIdx.x * 256 + threadIdx.x;
    if (i < HD * HD) {
        int k = i >> 6, c = i & 63;
        Wo_pad[i] = (c < NC) ? Wo[k * NC + c] : 0.f;
    }
    if (i < HD) bo_pad[i] = (i < NC) ? bo[i] : 0.f;
}

// ---------------- SpMM (bf16 h): sup = 0.9*(Ahat @ h_in) + 0.1*h0 ----------------

__global__ __launch_bounds__(256) void spmm_kernel(const ushort* __restrict__ h_in,
        const ushort* __restrict__ h0, ushort* __restrict__ sup,
        const float* __restrict__ dinv, const int* __restrict__ row_ptr,
        const EdgeT* __restrict__ ed, int n) {
    const int lane = threadIdx.x & 63;
    int wid = (blockIdx.x * 256 + threadIdx.x) >> 6;
    int nw = (gridDim.x * 256) >> 6;
    for (int node = wid; node < n; node += nw) {
        float di = dinv[node];
        float a0 = di * di * bf2f(h_in[(size_t)node * HD + lane]);
        float a1 = 0.f, a2 = 0.f, a3 = 0.f;
        int e = row_ptr[node], end = row_ptr[node + 1];
        for (; e + 4 <= end; e += 4) {
            EdgeT E0 = ed[e], E1 = ed[e + 1], E2 = ed[e + 2], E3 = ed[e + 3];
            a0 = fmaf(E0.v, bf2f(h_in[(size_t)E0.s * HD + lane]), a0);
            a1 = fmaf(E1.v, bf2f(h_in[(size_t)E1.s * HD + lane]), a1);
            a2 = fmaf(E2.v, bf2f(h_in[(size_t)E2.s * HD + lane]), a2);
            a3 = fmaf(E3.v, bf2f(h_in[(size_t)E3.s * HD + lane]), a3);
        }
        for (; e < end; ++e) {
            EdgeT E0 = ed[e];
            a0 = fmaf(E0.v, bf2f(h_in[(size_t)E0.s * HD + lane]), a0);
        }
        float acc = (a0 + a1) + (a2 + a3);
        float r = fmaf(0.9f, acc, 0.1f * bf2f(h0[(size_t)node * HD + lane]));
        sup[(size_t)node * HD + lane] = f2bf(r);
    }
}

// ---------------- proj: h0 = relu(x @ W_in + b_in), x fp32, out bf16 ----------------

__global__ __launch_bounds__(256) void proj_kernel(const float* __restrict__ x,
        const float* __restrict__ W, const float* __restrict__ bias,
        ushort* __restrict__ h0, int n) {
    __shared__ float Af[64 * 68];      // padded stride 68
    __shared__ float Wl[64 * 64];
    const int tid = threadIdx.x;
    const int tx = tid & 15;
    const int ty = tid >> 4;
    const int base = blockIdx.x * 64;
    const int kq = (tid & 15) * 4;
    const int rw = tid >> 4;

    float acc[4][4];
#pragma unroll
    for (int i = 0; i < 4; ++i)
#pragma unroll
        for (int j = 0; j < 4; ++j) acc[i][j] = 0.f;

    for (int kc = 0; kc < FIN; kc += 64) {
        __syncthreads();
#pragma unroll
        for (int p = 0; p < 4; ++p) {
            int row = rw + p * 16;
            int ng = base + row; if (ng >= n) ng = n - 1;
            *(float4*)(Af + row * 68 + kq) =
                *(const float4*)(x + (size_t)ng * FIN + kc + kq);
            *(float4*)(Wl + row * 64 + kq) =
                *(const float4*)(W + (size_t)(kc + row) * HD + kq);
        }
        __syncthreads();
#pragma unroll
        for (int kk = 0; kk < 64; kk += 4) {
            float4 a4[4];
#pragma unroll
            for (int i = 0; i < 4; ++i)
                a4[i] = *(const float4*)(Af + (ty * 4 + i) * 68 + kk);
#pragma unroll
            for (int k2 = 0; k2 < 4; ++k2) {
                float w[4];
                *(float4*)w = *(const float4*)(Wl + (kk + k2) * 64 + tx * 4);
#pragma unroll
                for (int i = 0; i < 4; ++i) {
                    float a = ((const float*)&a4[i])[k2];
#pragma unroll
                    for (int j = 0; j < 4; ++j) acc[i][j] = fmaf(a, w[j], acc[i][j]);
                }
            }
        }
    }

    float b[4];
#pragma unroll
    for (int j = 0; j < 4; ++j) b[j] = bias[tx * 4 + j];
#pragma unroll
    for (int i = 0; i < 4; ++i) {
        int ng = base + ty * 4 + i;
        if (ng < n) {
            ushort4 r;
            r.x = f2bf(fmaxf(acc[i][0] + b[0], 0.f));
            r.y = f2bf(fmaxf(acc[i][1] + b[1], 0.f));
            r.z = f2bf(fmaxf(acc[i][2] + b[2], 0.f));
            r.w = f2bf(fmaxf(acc[i][3] + b[3], 0.f));
            *(ushort4*)(h0 + (size_t)ng * HD + tx * 4) = r;
        }
    }
}

// ---------------- layer / output GEMM over bf16 A, fp32 W, K=64 ----------------

template<int MODE>
__global__ __launch_bounds__(256) void lgemm_kernel(const ushort* __restrict__ A,
        const float* __restrict__ W, const float* __restrict__ bias,
        ushort* __restrict__ C, float* __restrict__ outp, int n, float beta) {
    __shared__ float Af[64 * 68];
    __shared__ float Wl[64 * 64];
    const int tid = threadIdx.x;
    const int tx = tid & 15;
    const int ty = tid >> 4;
    const int base = blockIdx.x * 64;
    const int kq = (tid & 15) * 4;
    const int rw = tid >> 4;

#pragma unroll
    for (int p = 0; p < 4; ++p) {
        int row = rw + p * 16;
        int ng = base + row; if (ng >= n) ng = n - 1;
        ushort4 u = *(const ushort4*)(A + (size_t)ng * HD + kq);
        Af[row * 68 + kq + 0] = bf2f(u.x);
        Af[row * 68 + kq + 1] = bf2f(u.y);
        Af[row * 68 + kq + 2] = bf2f(u.z);
        Af[row * 68 + kq + 3] = bf2f(u.w);
        *(float4*)(Wl + row * 64 + kq) =
            *(const float4*)(W + (size_t)row * HD + kq);
    }
    __syncthreads();

    float acc[4][4];
#pragma unroll
    for (int i = 0; i < 4; ++i)
#pragma unroll
        for (int j = 0; j < 4; ++j) acc[i][j] = 0.f;

#pragma unroll
    for (int kk = 0; kk < 64; kk += 4) {
        float4 a4[4];
#pragma unroll
        for (int i = 0; i < 4; ++i)
            a4[i] = *(const float4*)(Af + (ty * 4 + i) * 68 + kk);
#pragma unroll
        for (int k2 = 0; k2 < 4; ++k2) {
            float w[4];
            *(float4*)w = *(const float4*)(Wl + (kk + k2) * 64 + tx * 4);
#pragma unroll
            for (int i = 0; i < 4; ++i) {
                float a = ((const float*)&a4[i])[k2];
#pragma unroll
                for (int j = 0; j < 4; ++j) acc[i][j] = fmaf(a, w[j], acc[i][j]);
            }
        }
    }

    if constexpr (MODE == 1) {
        const float ombeta = 1.f - beta;
#pragma unroll
        for (int i = 0; i < 4; ++i) {
            int ng = base + ty * 4 + i;
            if (ng < n) {
                ushort4 r;
                float s0 = Af[(ty * 4 + i) * 68 + tx * 4 + 0];
                float s1 = Af[(ty * 4 + i) * 68 + tx * 4 + 1];
                float s2 = Af[(ty * 4 + i) * 68 + tx * 4 + 2];
                float s3 = Af[(ty * 4 + i) * 68 + tx * 4 + 3];
                r.x = f2bf(fmaxf(fmaf(beta, acc[i][0], ombeta * s0), 0.f));
                r.y = f2bf(fmaxf(fmaf(beta, acc[i][1], ombeta * s1), 0.f));
                r.z = f2bf(fmaxf(fmaf(beta, acc[i][2], ombeta * s2), 0.f));
                r.w = f2bf(fmaxf(fmaf(beta, acc[i][3], ombeta * s3), 0.f));
                *(ushort4*)(C + (size_t)ng * HD + tx * 4) = r;
            }
        }
    } else {
        float b[4];
#pragma unroll
        for (int j = 0; j < 4; ++j) b[j] = bias[tx * 4 + j];
        const bool valid = (tx < 10);
#pragma unroll
        for (int i = 0; i < 4; ++i) {
            float lo[4];
            float m = -3.0e38f;
#pragma unroll
            for (int j = 0; j < 4; ++j) {
                lo[j] = acc[i][j] + b[j];
                if (valid) m = fmaxf(m, lo[j]);
            }
#pragma unroll
            for (int off = 1; off < 16; off <<= 1)
                m = fmaxf(m, __shfl_xor(m, off, 64));
            float s = 0.f;
            if (valid) {
#pragma unroll
                for (int j = 0; j < 4; ++j) s += __expf(lo[j] - m);
            }
#pragma unroll
            for (int off = 1; off < 16; off <<= 1)
                s += __shfl_xor(s, off, 64);
            float lse = __logf(s);
            int ng = base + ty * 4 + i;
            if (ng < n && valid) {
                float4 r;
                r.x = lo[0] - m - lse; r.y = lo[1] - m - lse;
                r.z = lo[2] - m - lse; r.w = lo[3] - m - lse;
                *(float4*)(outp + (size_t)ng * NC + tx * 4) = r;
            }
        }
    }
}

// ---------------- launch ----------------

extern "C" void kernel_launch(void* const* d_in, const int* in_sizes, int n_in,
                              void* d_out, int out_size, void* d_ws, size_t ws_size,
                              hipStream_t stream) {
    const float* x        = (const float*)d_in[0];
    const int*   eidx     = (const int*)d_in[1];
    const float* ew       = (const float*)d_in[2];
    const float* W_in     = (const float*)d_in[3];
    const float* b_in     = (const float*)d_in[4];
    const float* W_layers = (const float*)d_in[5];
    const float* W_out    = (const float*)d_in[6];
    const float* b_out    = (const float*)d_in[7];
    float* out = (float*)d_out;

    const int N = in_sizes[0] / FIN;
    const int E = in_sizes[2];
    const int L = in_sizes[5] / (HD * HD);
    const int* src = eidx;
    const int* dst = eidx + E;

    size_t off = 0;
    auto carve = [&](size_t bytes) {
        void* p = (char*)d_ws + off;
        off += (bytes + 255) & ~(size_t)255;
        return p;
    };
    unsigned long long* packed = (unsigned long long*)carve((size_t)N * 8);
    float*  dinv    = (float*)carve((size_t)N * 4);
    int*    row_ptr = (int*)  carve((size_t)(N + 1) * 4);
    int*    bsums   = (int*)  carve(512 * 4);
    float*  Wo_pad  = (float*)carve((size_t)HD * HD * 4);
    float*  bo_pad  = (float*)carve((size_t)HD * 4);
    ushort* rank    = (ushort*)carve((size_t)E * 2);
    EdgeT*  ed      = (EdgeT*)carve((size_t)E * 8);
    ushort* h0      = (ushort*)carve((size_t)N * HD * 2);
    ushort* hA      = (ushort*)carve((size_t)N * HD * 2);
    ushort* hB      = (ushort*)carve((size_t)N * HD * 2);
    (void)ws_size;

    const int NB = (N + 255) / 256;
    const int EB = (E + 255) / 256;

    initp_kernel<<<NB, 256, 0, stream>>>(packed, N);
    histp_kernel<<<EB, 256, 0, stream>>>(dst, ew, packed, rank, E);
    dinvp_kernel<<<NB, 256, 0, stream>>>(packed, dinv, N);
    scan_block_kernel<<<NB, 256, 0, stream>>>(packed, row_ptr, bsums, N);
    scan_top_kernel<<<1, 512, 0, stream>>>(bsums, NB);
    scan_add_kernel<<<NB, 256, 0, stream>>>(row_ptr, bsums, N, E);
    scatter_kernel<<<EB, 256, 0, stream>>>(src, dst, ew, dinv, row_ptr, rank, ed, E);
    pad_kernel<<<16, 256, 0, stream>>>(W_out, b_out, Wo_pad, bo_pad);

    const int NT = (N + 63) / 64;

    proj_kernel<<<NT, 256, 0, stream>>>(x, W_in, b_in, h0, N);

    const ushort* cur = h0;
    ushort* bufs[2] = { hA, hB };
    for (int i = 0; i < L; ++i) {
        float beta = logf(0.5f / (float)(i + 1) + 1.0f);
        ushort* sup = bufs[i & 1];
        spmm_kernel<<<2048, 256, 0, stream>>>(cur, h0, sup, dinv, row_ptr, ed, N);
        lgemm_kernel<1><<<NT, 256, 0, stream>>>(sup, W_layers + (size_t)i * HD * HD,
                                                nullptr, sup, nullptr, N, beta);
        cur = sup;
    }

    lgemm_kernel<2><<<NT, 256, 0, stream>>>(cur, Wo_pad, bo_pad, nullptr, out, N, 0.f);
}

// Round 5
// 641.126 us; speedup vs baseline: 1.2741x; 1.1125x over previous
//
#include <hip/hip_runtime.h>
#include <math.h>

#define HD 64
#define FIN 512
#define NC 40

struct __align__(8) EdgeT { int s; float v; };

__device__ __forceinline__ float bf2f(ushort u) {
    return __uint_as_float(((unsigned int)u) << 16);
}
__device__ __forceinline__ ushort f2bf(float f) {
    unsigned int u = __float_as_uint(f);
    unsigned int r = (u + 0x7fffu + ((u >> 16) & 1u)) >> 16;   // RNE
    return (ushort)r;
}
__device__ __forceinline__ float bflo(unsigned int u) {
    return __uint_as_float(u << 16);
}
__device__ __forceinline__ float bfhi(unsigned int u) {
    return __uint_as_float(u & 0xffff0000u);
}

// ---------------- graph preprocessing ----------------
// packed4[c*n+i]: bits[48:64) = edge count, bits[0:48) = fixed-point(2^-32) weighted degree.
// 4 shadow copies (c = edge_id & 3) cut atomic contention 4x. Fixed-point sum is order-exact.

__global__ __launch_bounds__(256) void initp_kernel(unsigned long long* packed4, int n) {
    int i = blockIdx.x * 256 + threadIdx.x;
    if (i < 4 * n) packed4[i] = (i < n) ? (1ULL << 32) : 0ULL;  // self-loop w=1 in copy 0
}

__global__ __launch_bounds__(256) void histp_kernel(const int* __restrict__ dst,
        const float* __restrict__ w, unsigned long long* packed4,
        ushort* __restrict__ rank, int E, int n) {
    int i = blockIdx.x * 256 + threadIdx.x;
    if (i < E) {
        int d = dst[i];
        int c = i & 3;
        unsigned long long add = (1ULL << 48) |
            (unsigned long long)(w[i] * 4294967296.0f);
        unsigned long long old = atomicAdd(&packed4[(size_t)c * n + d], add);
        rank[i] = (ushort)(old >> 48);
    }
}

// fused: dinv + copy-base + per-block count scan
__global__ __launch_bounds__(256) void post_kernel(const unsigned long long* __restrict__ packed4,
        float* __restrict__ dinv, uint* __restrict__ cbase,
        int* __restrict__ row_ptr, int* __restrict__ bsums, int n) {
    __shared__ int s[256];
    const unsigned long long M = 0xFFFFFFFFFFFFULL;
    int t = threadIdx.x;
    int i = blockIdx.x * 256 + t;
    int cnt = 0;
    if (i < n) {
        unsigned long long p0 = packed4[i];
        unsigned long long p1 = packed4[(size_t)n + i];
        unsigned long long p2 = packed4[(size_t)2 * n + i];
        unsigned long long p3 = packed4[(size_t)3 * n + i];
        int c0 = (int)(p0 >> 48), c1 = (int)(p1 >> 48);
        int c2 = (int)(p2 >> 48), c3 = (int)(p3 >> 48);
        unsigned long long fx = (p0 & M) + (p1 & M) + (p2 & M) + (p3 & M);
        float deg = (float)((double)fx * (1.0 / 4294967296.0));
        dinv[i] = rsqrtf(deg);                     // deg >= 1 (self-loop)
        cbase[i] = ((unsigned)(c0) << 8) | ((unsigned)(c0 + c1) << 16) |
                   ((unsigned)(c0 + c1 + c2) << 24);   // byte c = base of copy c
        cnt = c0 + c1 + c2 + c3;
    }
    s[t] = cnt; __syncthreads();
    for (int off = 1; off < 256; off <<= 1) {
        int u = (t >= off) ? s[t - off] : 0;
        __syncthreads();
        s[t] += u;
        __syncthreads();
    }
    if (i < n) row_ptr[i] = s[t] - cnt;
    if (t == 255) bsums[blockIdx.x] = s[255];
}

__global__ __launch_bounds__(512) void scan_top_kernel(int* bsums, int nb) {
    __shared__ int s[512];
    int t = threadIdx.x;
    int v = (t < nb) ? bsums[t] : 0;
    s[t] = v; __syncthreads();
    for (int off = 1; off < 512; off <<= 1) {
        int u = (t >= off) ? s[t - off] : 0;
        __syncthreads();
        s[t] += u;
        __syncthreads();
    }
    if (t < nb) bsums[t] = s[t] - v;
}

__global__ __launch_bounds__(256) void scan_add_kernel(int* __restrict__ row_ptr,
        const int* __restrict__ bsums, int n, int E) {
    int i = blockIdx.x * 256 + threadIdx.x;
    if (i < n) row_ptr[i] += bsums[blockIdx.x];
    if (i == 0) row_ptr[n] = E;
}

__global__ __launch_bounds__(256) void scatter_kernel(const int* __restrict__ src,
        const int* __restrict__ dst, const float* __restrict__ w,
        const float* __restrict__ dinv, const int* __restrict__ row_ptr,
        const uint* __restrict__ cbase, const ushort* __restrict__ rank,
        EdgeT* __restrict__ ed, int E) {
    int i = blockIdx.x * 256 + threadIdx.x;
    if (i < E) {
        int s = src[i], d = dst[i];
        int c = i & 3;
        int base = (cbase[d] >> (8 * c)) & 0xff;
        int pos = row_ptr[d] + base + (int)rank[i];
        EdgeT e; e.s = s; e.v = dinv[s] * w[i] * dinv[d];
        ed[pos] = e;
    }
}

__global__ __launch_bounds__(256) void pad_kernel(const float* __restrict__ Wo,
        const float* __restrict__ bo, float* __restrict__ Wo_pad,
        float* __restrict__ bo_pad) {
    int i = blockIdx.x * 256 + threadIdx.x;
    if (i < HD * HD) {
        int k = i >> 6, c = i & 63;
        Wo_pad[i] = (c < NC) ? Wo[k * NC + c] : 0.f;
    }
    if (i < HD) bo_pad[i] = (i < NC) ? bo[i] : 0.f;
}

// ---------------- SpMM v2 (bf16 h, 2 nodes/wave): sup = 0.9*(Ahat@h_in) + 0.1*h0 ----
// lane<32 -> node 2p, lane>=32 -> node 2p+1; each lane owns feature pair (lane&31)*2.

__global__ __launch_bounds__(256) void spmm_kernel(const ushort* __restrict__ h_in,
        const ushort* __restrict__ h0, ushort* __restrict__ sup,
        const float* __restrict__ dinv, const int* __restrict__ row_ptr,
        const EdgeT* __restrict__ ed, int n) {
    const int lane = threadIdx.x & 63;
    const int half = lane >> 5;
    const int fp = (lane & 31) * 2;
    int wid = (blockIdx.x * 256 + threadIdx.x) >> 6;
    int nw = (gridDim.x * 256) >> 6;
    int npairs = (n + 1) >> 1;
    for (int pair = wid; pair < npairs; pair += nw) {
        int node = pair * 2 + half;
        bool valid = node < n;
        int nc = valid ? node : n - 1;
        float di = dinv[nc];
        float sw = di * di;
        unsigned int us = *(const unsigned int*)(h_in + (size_t)nc * HD + fp);
        float a0 = sw * bflo(us), b0 = sw * bfhi(us);
        float a1 = 0.f, b1 = 0.f, a2 = 0.f, b2 = 0.f, a3 = 0.f, b3 = 0.f;
        int e = row_ptr[nc], end = row_ptr[nc + 1];
        for (; e + 4 <= end; e += 4) {
            EdgeT E0 = ed[e], E1 = ed[e + 1], E2 = ed[e + 2], E3 = ed[e + 3];
            unsigned int u0 = *(const unsigned int*)(h_in + (size_t)E0.s * HD + fp);
            unsigned int u1 = *(const unsigned int*)(h_in + (size_t)E1.s * HD + fp);
            unsigned int u2 = *(const unsigned int*)(h_in + (size_t)E2.s * HD + fp);
            unsigned int u3 = *(const unsigned int*)(h_in + (size_t)E3.s * HD + fp);
            a0 = fmaf(E0.v, bflo(u0), a0); b0 = fmaf(E0.v, bfhi(u0), b0);
            a1 = fmaf(E1.v, bflo(u1), a1); b1 = fmaf(E1.v, bfhi(u1), b1);
            a2 = fmaf(E2.v, bflo(u2), a2); b2 = fmaf(E2.v, bfhi(u2), b2);
            a3 = fmaf(E3.v, bflo(u3), a3); b3 = fmaf(E3.v, bfhi(u3), b3);
        }
        for (; e < end; ++e) {
            EdgeT E0 = ed[e];
            unsigned int u0 = *(const unsigned int*)(h_in + (size_t)E0.s * HD + fp);
            a0 = fmaf(E0.v, bflo(u0), a0); b0 = fmaf(E0.v, bfhi(u0), b0);
        }
        float accA = (a0 + a1) + (a2 + a3);
        float accB = (b0 + b1) + (b2 + b3);
        unsigned int uh = *(const unsigned int*)(h0 + (size_t)nc * HD + fp);
        float rA = fmaf(0.9f, accA, 0.1f * bflo(uh));
        float rB = fmaf(0.9f, accB, 0.1f * bfhi(uh));
        if (valid) {
            unsigned int pk = (unsigned int)f2bf(rA) | ((unsigned int)f2bf(rB) << 16);
            *(unsigned int*)(sup + (size_t)node * HD + fp) = pk;
        }
    }
}

// ---------------- proj: h0 = relu(x @ W_in + b_in), x fp32, out bf16 ----------------

__global__ __launch_bounds__(256) void proj_kernel(const float* __restrict__ x,
        const float* __restrict__ W, const float* __restrict__ bias,
        ushort* __restrict__ h0, int n) {
    __shared__ float Af[64 * 68];      // padded stride 68
    __shared__ float Wl[64 * 64];
    const int tid = threadIdx.x;
    const int tx = tid & 15;
    const int ty = tid >> 4;
    const int base = blockIdx.x * 64;
    const int kq = (tid & 15) * 4;
    const int rw = tid >> 4;

    float acc[4][4];
#pragma unroll
    for (int i = 0; i < 4; ++i)
#pragma unroll
        for (int j = 0; j < 4; ++j) acc[i][j] = 0.f;

    for (int kc = 0; kc < FIN; kc += 64) {
        __syncthreads();
#pragma unroll
        for (int p = 0; p < 4; ++p) {
            int row = rw + p * 16;
            int ng = base + row; if (ng >= n) ng = n - 1;
            *(float4*)(Af + row * 68 + kq) =
                *(const float4*)(x + (size_t)ng * FIN + kc + kq);
            *(float4*)(Wl + row * 64 + kq) =
                *(const float4*)(W + (size_t)(kc + row) * HD + kq);
        }
        __syncthreads();
#pragma unroll
        for (int kk = 0; kk < 64; kk += 4) {
            float4 a4[4];
#pragma unroll
            for (int i = 0; i < 4; ++i)
                a4[i] = *(const float4*)(Af + (ty * 4 + i) * 68 + kk);
#pragma unroll
            for (int k2 = 0; k2 < 4; ++k2) {
                float w[4];
                *(float4*)w = *(const float4*)(Wl + (kk + k2) * 64 + tx * 4);
#pragma unroll
                for (int i = 0; i < 4; ++i) {
                    float a = ((const float*)&a4[i])[k2];
#pragma unroll
                    for (int j = 0; j < 4; ++j) acc[i][j] = fmaf(a, w[j], acc[i][j]);
                }
            }
        }
    }

    float b[4];
#pragma unroll
    for (int j = 0; j < 4; ++j) b[j] = bias[tx * 4 + j];
#pragma unroll
    for (int i = 0; i < 4; ++i) {
        int ng = base + ty * 4 + i;
        if (ng < n) {
            ushort4 r;
            r.x = f2bf(fmaxf(acc[i][0] + b[0], 0.f));
            r.y = f2bf(fmaxf(acc[i][1] + b[1], 0.f));
            r.z = f2bf(fmaxf(acc[i][2] + b[2], 0.f));
            r.w = f2bf(fmaxf(acc[i][3] + b[3], 0.f));
            *(ushort4*)(h0 + (size_t)ng * HD + tx * 4) = r;
        }
    }
}

// ---------------- layer / output GEMM over bf16 A, fp32 W, K=64 ----------------

template<int MODE>
__global__ __launch_bounds__(256) void lgemm_kernel(const ushort* __restrict__ A,
        const float* __restrict__ W, const float* __restrict__ bias,
        ushort* __restrict__ C, float* __restrict__ outp, int n, float beta) {
    __shared__ float Af[64 * 68];
    __shared__ float Wl[64 * 64];
    const int tid = threadIdx.x;
    const int tx = tid & 15;
    const int ty = tid >> 4;
    const int base = blockIdx.x * 64;
    const int kq = (tid & 15) * 4;
    const int rw = tid >> 4;

#pragma unroll
    for (int p = 0; p < 4; ++p) {
        int row = rw + p * 16;
        int ng = base + row; if (ng >= n) ng = n - 1;
        ushort4 u = *(const ushort4*)(A + (size_t)ng * HD + kq);
        Af[row * 68 + kq + 0] = bf2f(u.x);
        Af[row * 68 + kq + 1] = bf2f(u.y);
        Af[row * 68 + kq + 2] = bf2f(u.z);
        Af[row * 68 + kq + 3] = bf2f(u.w);
        *(float4*)(Wl + row * 64 + kq) =
            *(const float4*)(W + (size_t)row * HD + kq);
    }
    __syncthreads();

    float acc[4][4];
#pragma unroll
    for (int i = 0; i < 4; ++i)
#pragma unroll
        for (int j = 0; j < 4; ++j) acc[i][j] = 0.f;

#pragma unroll
    for (int kk = 0; kk < 64; kk += 4) {
        float4 a4[4];
#pragma unroll
        for (int i = 0; i < 4; ++i)
            a4[i] = *(const float4*)(Af + (ty * 4 + i) * 68 + kk);
#pragma unroll
        for (int k2 = 0; k2 < 4; ++k2) {
            float w[4];
            *(float4*)w = *(const float4*)(Wl + (kk + k2) * 64 + tx * 4);
#pragma unroll
            for (int i = 0; i < 4; ++i) {
                float a = ((const float*)&a4[i])[k2];
#pragma unroll
                for (int j = 0; j < 4; ++j) acc[i][j] = fmaf(a, w[j], acc[i][j]);
            }
        }
    }

    if constexpr (MODE == 1) {
        const float ombeta = 1.f - beta;
#pragma unroll
        for (int i = 0; i < 4; ++i) {
            int ng = base + ty * 4 + i;
            if (ng < n) {
                ushort4 r;
                float s0 = Af[(ty * 4 + i) * 68 + tx * 4 + 0];
                float s1 = Af[(ty * 4 + i) * 68 + tx * 4 + 1];
                float s2 = Af[(ty * 4 + i) * 68 + tx * 4 + 2];
                float s3 = Af[(ty * 4 + i) * 68 + tx * 4 + 3];
                r.x = f2bf(fmaxf(fmaf(beta, acc[i][0], ombeta * s0), 0.f));
                r.y = f2bf(fmaxf(fmaf(beta, acc[i][1], ombeta * s1), 0.f));
                r.z = f2bf(fmaxf(fmaf(beta, acc[i][2], ombeta * s2), 0.f));
                r.w = f2bf(fmaxf(fmaf(beta, acc[i][3], ombeta * s3), 0.f));
                *(ushort4*)(C + (size_t)ng * HD + tx * 4) = r;
            }
        }
    } else {
        float b[4];
#pragma unroll
        for (int j = 0; j < 4; ++j) b[j] = bias[tx * 4 + j];
        const bool valid = (tx < 10);
#pragma unroll
        for (int i = 0; i < 4; ++i) {
            float lo[4];
            float m = -3.0e38f;
#pragma unroll
            for (int j = 0; j < 4; ++j) {
                lo[j] = acc[i][j] + b[j];
                if (valid) m = fmaxf(m, lo[j]);
            }
#pragma unroll
            for (int off = 1; off < 16; off <<= 1)
                m = fmaxf(m, __shfl_xor(m, off, 64));
            float s = 0.f;
            if (valid) {
#pragma unroll
                for (int j = 0; j < 4; ++j) s += __expf(lo[j] - m);
            }
#pragma unroll
            for (int off = 1; off < 16; off <<= 1)
                s += __shfl_xor(s, off, 64);
            float lse = __logf(s);
            int ng = base + ty * 4 + i;
            if (ng < n && valid) {
                float4 r;
                r.x = lo[0] - m - lse; r.y = lo[1] - m - lse;
                r.z = lo[2] - m - lse; r.w = lo[3] - m - lse;
                *(float4*)(outp + (size_t)ng * NC + tx * 4) = r;
            }
        }
    }
}

// ---------------- launch ----------------

extern "C" void kernel_launch(void* const* d_in, const int* in_sizes, int n_in,
                              void* d_out, int out_size, void* d_ws, size_t ws_size,
                              hipStream_t stream) {
    const float* x        = (const float*)d_in[0];
    const int*   eidx     = (const int*)d_in[1];
    const float* ew       = (const float*)d_in[2];
    const float* W_in     = (const float*)d_in[3];
    const float* b_in     = (const float*)d_in[4];
    const float* W_layers = (const float*)d_in[5];
    const float* W_out    = (const float*)d_in[6];
    const float* b_out    = (const float*)d_in[7];
    float* out = (float*)d_out;

    const int N = in_sizes[0] / FIN;
    const int E = in_sizes[2];
    const int L = in_sizes[5] / (HD * HD);
    const int* src = eidx;
    const int* dst = eidx + E;

    size_t off = 0;
    auto carve = [&](size_t bytes) {
        void* p = (char*)d_ws + off;
        off += (bytes + 255) & ~(size_t)255;
        return p;
    };
    unsigned long long* packed4 = (unsigned long long*)carve((size_t)N * 4 * 8);
    float*  dinv    = (float*)carve((size_t)N * 4);
    uint*   cbase   = (uint*) carve((size_t)N * 4);
    int*    row_ptr = (int*)  carve((size_t)(N + 1) * 4);
    int*    bsums   = (int*)  carve(512 * 4);
    float*  Wo_pad  = (float*)carve((size_t)HD * HD * 4);
    float*  bo_pad  = (float*)carve((size_t)HD * 4);
    ushort* rank    = (ushort*)carve((size_t)E * 2);
    EdgeT*  ed      = (EdgeT*)carve((size_t)E * 8);
    ushort* h0      = (ushort*)carve((size_t)N * HD * 2);
    ushort* hA      = (ushort*)carve((size_t)N * HD * 2);
    ushort* hB      = (ushort*)carve((size_t)N * HD * 2);
    (void)ws_size;

    const int NB = (N + 255) / 256;
    const int EB = (E + 255) / 256;

    initp_kernel<<<(4 * N + 255) / 256, 256, 0, stream>>>(packed4, N);
    histp_kernel<<<EB, 256, 0, stream>>>(dst, ew, packed4, rank, E, N);
    post_kernel<<<NB, 256, 0, stream>>>(packed4, dinv, cbase, row_ptr, bsums, N);
    scan_top_kernel<<<1, 512, 0, stream>>>(bsums, NB);
    scan_add_kernel<<<NB, 256, 0, stream>>>(row_ptr, bsums, N, E);
    scatter_kernel<<<EB, 256, 0, stream>>>(src, dst, ew, dinv, row_ptr, cbase, rank, ed, E);
    pad_kernel<<<16, 256, 0, stream>>>(W_out, b_out, Wo_pad, bo_pad);

    const int NT = (N + 63) / 64;

    proj_kernel<<<NT, 256, 0, stream>>>(x, W_in, b_in, h0, N);

    const ushort* cur = h0;
    ushort* bufs[2] = { hA, hB };
    for (int i = 0; i < L; ++i) {
        float beta = logf(0.5f / (float)(i + 1) + 1.0f);
        ushort* sup = bufs[i & 1];
        spmm_kernel<<<2048, 256, 0, stream>>>(cur, h0, sup, dinv, row_ptr, ed, N);
        lgemm_kernel<1><<<NT, 256, 0, stream>>>(sup, W_layers + (size_t)i * HD * HD,
                                                nullptr, sup, nullptr, N, beta);
        cur = sup;
    }

    lgemm_kernel<2><<<NT, 256, 0, stream>>>(cur, Wo_pad, bo_pad, nullptr, out, N, 0.f);
}

// Round 6
// 560.947 us; speedup vs baseline: 1.4562x; 1.1429x over previous
//
#include <hip/hip_runtime.h>
#include <math.h>

#define HD 64
#define FIN 512
#define NC 40

struct __align__(8) EdgeT { int s; float v; };

typedef __attribute__((ext_vector_type(8))) short bf16x8;
typedef __attribute__((ext_vector_type(4))) float f32x4;

__device__ __forceinline__ float bf2f(ushort u) {
    return __uint_as_float(((unsigned int)u) << 16);
}
__device__ __forceinline__ ushort f2bf(float f) {
    unsigned int u = __float_as_uint(f);
    unsigned int r = (u + 0x7fffu + ((u >> 16) & 1u)) >> 16;   // RNE
    return (ushort)r;
}

// ---------------- graph preprocessing ----------------
// packed4[c*n+i]: bits[48:64) = edge count, bits[0:48) = fixed-point(2^-32) weighted degree.

__global__ __launch_bounds__(256) void initp_kernel(unsigned long long* packed4, int n) {
    int i = blockIdx.x * 256 + threadIdx.x;
    if (i < 4 * n) packed4[i] = (i < n) ? (1ULL << 32) : 0ULL;  // self-loop w=1 in copy 0
}

__global__ __launch_bounds__(256) void histp_kernel(const int* __restrict__ dst,
        const float* __restrict__ w, unsigned long long* packed4,
        ushort* __restrict__ rank, int E, int n) {
    int i = blockIdx.x * 256 + threadIdx.x;
    if (i < E) {
        int d = dst[i];
        int c = i & 3;
        unsigned long long add = (1ULL << 48) |
            (unsigned long long)(w[i] * 4294967296.0f);
        unsigned long long old = atomicAdd(&packed4[(size_t)c * n + d], add);
        rank[i] = (ushort)(old >> 48);
    }
}

__global__ __launch_bounds__(256) void post_kernel(const unsigned long long* __restrict__ packed4,
        float* __restrict__ dinv, uint* __restrict__ cbase,
        int* __restrict__ row_ptr, int* __restrict__ bsums, int n) {
    __shared__ int s[256];
    const unsigned long long M = 0xFFFFFFFFFFFFULL;
    int t = threadIdx.x;
    int i = blockIdx.x * 256 + t;
    int cnt = 0;
    if (i < n) {
        unsigned long long p0 = packed4[i];
        unsigned long long p1 = packed4[(size_t)n + i];
        unsigned long long p2 = packed4[(size_t)2 * n + i];
        unsigned long long p3 = packed4[(size_t)3 * n + i];
        int c0 = (int)(p0 >> 48), c1 = (int)(p1 >> 48);
        int c2 = (int)(p2 >> 48), c3 = (int)(p3 >> 48);
        unsigned long long fx = (p0 & M) + (p1 & M) + (p2 & M) + (p3 & M);
        float deg = (float)((double)fx * (1.0 / 4294967296.0));
        dinv[i] = rsqrtf(deg);
        cbase[i] = ((unsigned)(c0) << 8) | ((unsigned)(c0 + c1) << 16) |
                   ((unsigned)(c0 + c1 + c2) << 24);
        cnt = c0 + c1 + c2 + c3;
    }
    s[t] = cnt; __syncthreads();
    for (int off = 1; off < 256; off <<= 1) {
        int u = (t >= off) ? s[t - off] : 0;
        __syncthreads();
        s[t] += u;
        __syncthreads();
    }
    if (i < n) row_ptr[i] = s[t] - cnt;
    if (t == 255) bsums[blockIdx.x] = s[255];
}

__global__ __launch_bounds__(512) void scan_top_kernel(int* bsums, int nb) {
    __shared__ int s[512];
    int t = threadIdx.x;
    int v = (t < nb) ? bsums[t] : 0;
    s[t] = v; __syncthreads();
    for (int off = 1; off < 512; off <<= 1) {
        int u = (t >= off) ? s[t - off] : 0;
        __syncthreads();
        s[t] += u;
        __syncthreads();
    }
    if (t < nb) bsums[t] = s[t] - v;
}

__global__ __launch_bounds__(256) void scan_add_kernel(int* __restrict__ row_ptr,
        const int* __restrict__ bsums, int n, int E) {
    int i = blockIdx.x * 256 + threadIdx.x;
    if (i < n) row_ptr[i] += bsums[blockIdx.x];
    if (i == 0) row_ptr[n] = E;
}

__global__ __launch_bounds__(256) void scatter_kernel(const int* __restrict__ src,
        const int* __restrict__ dst, const float* __restrict__ w,
        const float* __restrict__ dinv, const int* __restrict__ row_ptr,
        const uint* __restrict__ cbase, const ushort* __restrict__ rank,
        EdgeT* __restrict__ ed, int E) {
    int i = blockIdx.x * 256 + threadIdx.x;
    if (i < E) {
        int s = src[i], d = dst[i];
        int c = i & 3;
        int base = (cbase[d] >> (8 * c)) & 0xff;
        int pos = row_ptr[d] + base + (int)rank[i];
        EdgeT e; e.s = s; e.v = dinv[s] * w[i] * dinv[d];
        ed[pos] = e;
    }
}

__global__ __launch_bounds__(256) void pad_kernel(const float* __restrict__ Wo,
        const float* __restrict__ bo, float* __restrict__ Wo_pad,
        float* __restrict__ bo_pad) {
    int i = blockIdx.x * 256 + threadIdx.x;
    if (i < HD * HD) {
        int k = i >> 6, c = i & 63;
        Wo_pad[i] = (c < NC) ? Wo[k * NC + c] : 0.f;
    }
    if (i < HD) bo_pad[i] = (i < NC) ? bo[i] : 0.f;
}

// W_in (512x64 f32) -> bf16 fragment-major: Wf[((c*4+t)*64+l)*8+j] = W[c*32+8*(l>>4)+j][t*16+(l&15)]
__global__ __launch_bounds__(256) void wfrag_kernel(const float* __restrict__ W,
        ushort* __restrict__ Wf) {
    int i = blockIdx.x * 256 + threadIdx.x;
    if (i < FIN * HD) {
        int j = i & 7;
        int l = (i >> 3) & 63;
        int t = (i >> 9) & 3;
        int c = i >> 11;
        int k = c * 32 + ((l >> 4) * 8) + j;
        int col = t * 16 + (l & 15);
        Wf[i] = f2bf(W[k * HD + col]);
    }
}

// ---------------- SpMM v3 (bf16 h, 4 nodes/wave): sup = 0.9*(Ahat@h_in) + 0.1*h0 ----
// 16 lanes per node; lane owns feature quad (lane&15)*4.

__global__ __launch_bounds__(256) void spmm_kernel(const ushort* __restrict__ h_in,
        const ushort* __restrict__ h0, ushort* __restrict__ sup,
        const float* __restrict__ dinv, const int* __restrict__ row_ptr,
        const EdgeT* __restrict__ ed, int n) {
    const int lane = threadIdx.x & 63;
    const int q = lane >> 4;
    const int fl = (lane & 15) * 4;
    int wid = (blockIdx.x * 256 + threadIdx.x) >> 6;
    int nw = (gridDim.x * 256) >> 6;
    int nquads = (n + 3) >> 2;
    for (int quad = wid; quad < nquads; quad += nw) {
        int node = quad * 4 + q;
        bool valid = node < n;
        int nc = valid ? node : n - 1;
        float di = dinv[nc];
        float sw = di * di;
        ushort4 us = *(const ushort4*)(h_in + (size_t)nc * HD + fl);
        float a0[4], a1[4] = {0,0,0,0}, a2[4] = {0,0,0,0}, a3[4] = {0,0,0,0};
        a0[0] = sw * bf2f(us.x); a0[1] = sw * bf2f(us.y);
        a0[2] = sw * bf2f(us.z); a0[3] = sw * bf2f(us.w);
        int e = row_ptr[nc], end = row_ptr[nc + 1];
        for (; e + 4 <= end; e += 4) {
            EdgeT E0 = ed[e], E1 = ed[e + 1], E2 = ed[e + 2], E3 = ed[e + 3];
            ushort4 u0 = *(const ushort4*)(h_in + (size_t)E0.s * HD + fl);
            ushort4 u1 = *(const ushort4*)(h_in + (size_t)E1.s * HD + fl);
            ushort4 u2 = *(const ushort4*)(h_in + (size_t)E2.s * HD + fl);
            ushort4 u3 = *(const ushort4*)(h_in + (size_t)E3.s * HD + fl);
            a0[0] = fmaf(E0.v, bf2f(u0.x), a0[0]); a0[1] = fmaf(E0.v, bf2f(u0.y), a0[1]);
            a0[2] = fmaf(E0.v, bf2f(u0.z), a0[2]); a0[3] = fmaf(E0.v, bf2f(u0.w), a0[3]);
            a1[0] = fmaf(E1.v, bf2f(u1.x), a1[0]); a1[1] = fmaf(E1.v, bf2f(u1.y), a1[1]);
            a1[2] = fmaf(E1.v, bf2f(u1.z), a1[2]); a1[3] = fmaf(E1.v, bf2f(u1.w), a1[3]);
            a2[0] = fmaf(E2.v, bf2f(u2.x), a2[0]); a2[1] = fmaf(E2.v, bf2f(u2.y), a2[1]);
            a2[2] = fmaf(E2.v, bf2f(u2.z), a2[2]); a2[3] = fmaf(E2.v, bf2f(u2.w), a2[3]);
            a3[0] = fmaf(E3.v, bf2f(u3.x), a3[0]); a3[1] = fmaf(E3.v, bf2f(u3.y), a3[1]);
            a3[2] = fmaf(E3.v, bf2f(u3.z), a3[2]); a3[3] = fmaf(E3.v, bf2f(u3.w), a3[3]);
        }
        for (; e < end; ++e) {
            EdgeT E0 = ed[e];
            ushort4 u0 = *(const ushort4*)(h_in + (size_t)E0.s * HD + fl);
            a0[0] = fmaf(E0.v, bf2f(u0.x), a0[0]); a0[1] = fmaf(E0.v, bf2f(u0.y), a0[1]);
            a0[2] = fmaf(E0.v, bf2f(u0.z), a0[2]); a0[3] = fmaf(E0.v, bf2f(u0.w), a0[3]);
        }
        if (valid) {
            ushort4 uh = *(const ushort4*)(h0 + (size_t)nc * HD + fl);
            ushort4 r;
            r.x = f2bf(fmaf(0.9f, (a0[0] + a1[0]) + (a2[0] + a3[0]), 0.1f * bf2f(uh.x)));
            r.y = f2bf(fmaf(0.9f, (a0[1] + a1[1]) + (a2[1] + a3[1]), 0.1f * bf2f(uh.y)));
            r.z = f2bf(fmaf(0.9f, (a0[2] + a1[2]) + (a2[2] + a3[2]), 0.1f * bf2f(uh.z)));
            r.w = f2bf(fmaf(0.9f, (a0[3] + a1[3]) + (a2[3] + a3[3]), 0.1f * bf2f(uh.w)));
            *(ushort4*)(sup + (size_t)node * HD + fl) = r;
        }
    }
}

// ---------------- proj (MFMA): h0 = relu(x @ W_in + b_in) -> bf16 ----------------
// wave: 32 nodes (2 M-frags) x 64 cols (4 N-frags); block = 4 waves = 128 nodes.

__global__ __launch_bounds__(256) void projm_kernel(const float* __restrict__ x,
        const ushort* __restrict__ Wf, const float* __restrict__ bias,
        ushort* __restrict__ h0, int n) {
    const int lane = threadIdx.x & 63;
    const int wave = threadIdx.x >> 6;
    const int row = lane & 15;
    const int g = lane >> 4;
    const int base = blockIdx.x * 128 + wave * 32;

    f32x4 acc[2][4];
#pragma unroll
    for (int m = 0; m < 2; ++m)
#pragma unroll
        for (int t = 0; t < 4; ++t) acc[m][t] = (f32x4){0.f, 0.f, 0.f, 0.f};

    for (int c = 0; c < 16; ++c) {
        bf16x8 afr[2];
#pragma unroll
        for (int m = 0; m < 2; ++m) {
            int node = base + m * 16 + row;
            if (node >= n) node = n - 1;
            const float* p = x + (size_t)node * FIN + c * 32 + g * 8;
            float4 v0 = *(const float4*)p;
            float4 v1 = *(const float4*)(p + 4);
            afr[m][0] = (short)f2bf(v0.x); afr[m][1] = (short)f2bf(v0.y);
            afr[m][2] = (short)f2bf(v0.z); afr[m][3] = (short)f2bf(v0.w);
            afr[m][4] = (short)f2bf(v1.x); afr[m][5] = (short)f2bf(v1.y);
            afr[m][6] = (short)f2bf(v1.z); afr[m][7] = (short)f2bf(v1.w);
        }
#pragma unroll
        for (int t = 0; t < 4; ++t) {
            bf16x8 bfr = *(const bf16x8*)(Wf + ((size_t)(c * 4 + t) * 64 + lane) * 8);
            acc[0][t] = __builtin_amdgcn_mfma_f32_16x16x32_bf16(afr[0], bfr, acc[0][t], 0, 0, 0);
            acc[1][t] = __builtin_amdgcn_mfma_f32_16x16x32_bf16(afr[1], bfr, acc[1][t], 0, 0, 0);
        }
    }

    float bj[4];
#pragma unroll
    for (int t = 0; t < 4; ++t) bj[t] = bias[t * 16 + row];
#pragma unroll
    for (int m = 0; m < 2; ++m)
#pragma unroll
        for (int r = 0; r < 4; ++r) {
            int node = base + m * 16 + g * 4 + r;
            if (node < n) {
#pragma unroll
                for (int t = 0; t < 4; ++t) {
                    float v = fmaxf(acc[m][t][r] + bj[t], 0.f);
                    h0[(size_t)node * HD + t * 16 + row] = f2bf(v);
                }
            }
        }
}

// ---------------- layer / output GEMM over bf16 A, fp32 W, K=64 ----------------

template<int MODE>
__global__ __launch_bounds__(256) void lgemm_kernel(const ushort* __restrict__ A,
        const float* __restrict__ W, const float* __restrict__ bias,
        ushort* __restrict__ C, float* __restrict__ outp, int n, float beta) {
    __shared__ float Af[64 * 68];
    __shared__ float Wl[64 * 64];
    const int tid = threadIdx.x;
    const int tx = tid & 15;
    const int ty = tid >> 4;
    const int base = blockIdx.x * 64;
    const int kq = (tid & 15) * 4;
    const int rw = tid >> 4;

#pragma unroll
    for (int p = 0; p < 4; ++p) {
        int row = rw + p * 16;
        int ng = base + row; if (ng >= n) ng = n - 1;
        ushort4 u = *(const ushort4*)(A + (size_t)ng * HD + kq);
        Af[row * 68 + kq + 0] = bf2f(u.x);
        Af[row * 68 + kq + 1] = bf2f(u.y);
        Af[row * 68 + kq + 2] = bf2f(u.z);
        Af[row * 68 + kq + 3] = bf2f(u.w);
        *(float4*)(Wl + row * 64 + kq) =
            *(const float4*)(W + (size_t)row * HD + kq);
    }
    __syncthreads();

    float acc[4][4];
#pragma unroll
    for (int i = 0; i < 4; ++i)
#pragma unroll
        for (int j = 0; j < 4; ++j) acc[i][j] = 0.f;

#pragma unroll
    for (int kk = 0; kk < 64; kk += 4) {
        float4 a4[4];
#pragma unroll
        for (int i = 0; i < 4; ++i)
            a4[i] = *(const float4*)(Af + (ty * 4 + i) * 68 + kk);
#pragma unroll
        for (int k2 = 0; k2 < 4; ++k2) {
            float w[4];
            *(float4*)w = *(const float4*)(Wl + (kk + k2) * 64 + tx * 4);
#pragma unroll
            for (int i = 0; i < 4; ++i) {
                float a = ((const float*)&a4[i])[k2];
#pragma unroll
                for (int j = 0; j < 4; ++j) acc[i][j] = fmaf(a, w[j], acc[i][j]);
            }
        }
    }

    if constexpr (MODE == 1) {
        const float ombeta = 1.f - beta;
#pragma unroll
        for (int i = 0; i < 4; ++i) {
            int ng = base + ty * 4 + i;
            if (ng < n) {
                ushort4 r;
                float s0 = Af[(ty * 4 + i) * 68 + tx * 4 + 0];
                float s1 = Af[(ty * 4 + i) * 68 + tx * 4 + 1];
                float s2 = Af[(ty * 4 + i) * 68 + tx * 4 + 2];
                float s3 = Af[(ty * 4 + i) * 68 + tx * 4 + 3];
                r.x = f2bf(fmaxf(fmaf(beta, acc[i][0], ombeta * s0), 0.f));
                r.y = f2bf(fmaxf(fmaf(beta, acc[i][1], ombeta * s1), 0.f));
                r.z = f2bf(fmaxf(fmaf(beta, acc[i][2], ombeta * s2), 0.f));
                r.w = f2bf(fmaxf(fmaf(beta, acc[i][3], ombeta * s3), 0.f));
                *(ushort4*)(C + (size_t)ng * HD + tx * 4) = r;
            }
        }
    } else {
        float b[4];
#pragma unroll
        for (int j = 0; j < 4; ++j) b[j] = bias[tx * 4 + j];
        const bool valid = (tx < 10);
#pragma unroll
        for (int i = 0; i < 4; ++i) {
            float lo[4];
            float m = -3.0e38f;
#pragma unroll
            for (int j = 0; j < 4; ++j) {
                lo[j] = acc[i][j] + b[j];
                if (valid) m = fmaxf(m, lo[j]);
            }
#pragma unroll
            for (int off = 1; off < 16; off <<= 1)
                m = fmaxf(m, __shfl_xor(m, off, 64));
            float s = 0.f;
            if (valid) {
#pragma unroll
                for (int j = 0; j < 4; ++j) s += __expf(lo[j] - m);
            }
#pragma unroll
            for (int off = 1; off < 16; off <<= 1)
                s += __shfl_xor(s, off, 64);
            float lse = __logf(s);
            int ng = base + ty * 4 + i;
            if (ng < n && valid) {
                float4 r;
                r.x = lo[0] - m - lse; r.y = lo[1] - m - lse;
                r.z = lo[2] - m - lse; r.w = lo[3] - m - lse;
                *(float4*)(outp + (size_t)ng * NC + tx * 4) = r;
            }
        }
    }
}

// ---------------- launch ----------------

extern "C" void kernel_launch(void* const* d_in, const int* in_sizes, int n_in,
                              void* d_out, int out_size, void* d_ws, size_t ws_size,
                              hipStream_t stream) {
    const float* x        = (const float*)d_in[0];
    const int*   eidx     = (const int*)d_in[1];
    const float* ew       = (const float*)d_in[2];
    const float* W_in     = (const float*)d_in[3];
    const float* b_in     = (const float*)d_in[4];
    const float* W_layers = (const float*)d_in[5];
    const float* W_out    = (const float*)d_in[6];
    const float* b_out    = (const float*)d_in[7];
    float* out = (float*)d_out;

    const int N = in_sizes[0] / FIN;
    const int E = in_sizes[2];
    const int L = in_sizes[5] / (HD * HD);
    const int* src = eidx;
    const int* dst = eidx + E;

    size_t off = 0;
    auto carve = [&](size_t bytes) {
        void* p = (char*)d_ws + off;
        off += (bytes + 255) & ~(size_t)255;
        return p;
    };
    unsigned long long* packed4 = (unsigned long long*)carve((size_t)N * 4 * 8);
    float*  dinv    = (float*)carve((size_t)N * 4);
    uint*   cbase   = (uint*) carve((size_t)N * 4);
    int*    row_ptr = (int*)  carve((size_t)(N + 1) * 4);
    int*    bsums   = (int*)  carve(512 * 4);
    float*  Wo_pad  = (float*)carve((size_t)HD * HD * 4);
    float*  bo_pad  = (float*)carve((size_t)HD * 4);
    ushort* Wf      = (ushort*)carve((size_t)FIN * HD * 2);
    ushort* rank    = (ushort*)carve((size_t)E * 2);
    EdgeT*  ed      = (EdgeT*)carve((size_t)E * 8);
    ushort* h0      = (ushort*)carve((size_t)N * HD * 2);
    ushort* hA      = (ushort*)carve((size_t)N * HD * 2);
    ushort* hB      = (ushort*)carve((size_t)N * HD * 2);
    (void)ws_size;

    const int NB = (N + 255) / 256;
    const int EB = (E + 255) / 256;

    initp_kernel<<<(4 * N + 255) / 256, 256, 0, stream>>>(packed4, N);
    histp_kernel<<<EB, 256, 0, stream>>>(dst, ew, packed4, rank, E, N);
    post_kernel<<<NB, 256, 0, stream>>>(packed4, dinv, cbase, row_ptr, bsums, N);
    scan_top_kernel<<<1, 512, 0, stream>>>(bsums, NB);
    scan_add_kernel<<<NB, 256, 0, stream>>>(row_ptr, bsums, N, E);
    scatter_kernel<<<EB, 256, 0, stream>>>(src, dst, ew, dinv, row_ptr, cbase, rank, ed, E);
    pad_kernel<<<16, 256, 0, stream>>>(W_out, b_out, Wo_pad, bo_pad);
    wfrag_kernel<<<(FIN * HD + 255) / 256, 256, 0, stream>>>(W_in, Wf);

    projm_kernel<<<(N + 127) / 128, 256, 0, stream>>>(x, Wf, b_in, h0, N);

    const int NT = (N + 63) / 64;
    const ushort* cur = h0;
    ushort* bufs[2] = { hA, hB };
    for (int i = 0; i < L; ++i) {
        float beta = logf(0.5f / (float)(i + 1) + 1.0f);
        ushort* sup = bufs[i & 1];
        spmm_kernel<<<2048, 256, 0, stream>>>(cur, h0, sup, dinv, row_ptr, ed, N);
        lgemm_kernel<1><<<NT, 256, 0, stream>>>(sup, W_layers + (size_t)i * HD * HD,
                                                nullptr, sup, nullptr, N, beta);
        cur = sup;
    }

    lgemm_kernel<2><<<NT, 256, 0, stream>>>(cur, Wo_pad, bo_pad, nullptr, out, N, 0.f);
}